// Round 12
// baseline (1301.505 us; speedup 1.0000x reference)
//
#include <hip/hip_runtime.h>

// EqProp MLP relaxation (784->128->128->10, B=16384, T=60), FUSED all-FP32 kernel.
// PRECISION FINDING (prev session): W1 ~ N(0,1/128) -> edge of chaos; errors
// amplified ~260x; everything stays fp32-grade.
// R10 (1266us, best): wave specialization (A: h1'+h3' reads h2; B: h2' reads
// h1+h3) + depth-1 weight pipeline. 124 VGPR, 2 waves/SIMD, conflicts nil,
// VALUBusy 72%. Remaining idle ~14k cy/step/CU: (i) task B ends with 80
// latency-exposed h3 VMEM loads right before the barrier; (ii) residual lgkm
// waits. Reg-cap triangle (R6/R7/R8) forbids deeper reg pipelines; LDS full.
// R11 (zero new persistent regs) [RESUBMIT: R11 bench was an infra failure
// ("container failed twice"), not a kernel verdict — no data, same theory]:
//   * Task B: load OWN-column h3 (8 scalar VMEM) at STEP START, move the
//     h3@W2 contribution BEFORE the k-loop, broadcast via __shfl(h3own,kk,32)
//     (lane kk loaded col kk). 80 late VMEM -> 8 early VMEM; tail gone.
//   * Task A: issue w2r global load before the chunk's state reads (its L1
//     latency hides under their lgkm wait).
// Geometry unchanged: NT=512, ROWS=64, R=8 rows x 4 cols per task thread,
// grid=256 = 1 blk/CU. LDS: W1 64K full-period swizzle (chunk of W1[r][c] at
// (r<<5)|((c>>2)^(r>>2)), both patterns read co=(jg^c)<<2, conflict-free) +
// h1 32K + h2 32K + c1 32K = 163840 B. h3 exchanges A->B via out[H3O].

#define NB 16384
#define D0 784
#define D1 128
#define D3 10
#define TSTEPS 60
#define NT 512
#define ROWS 64
#define R 8                              // rows per thread within a task
#define NBLK (NB / ROWS)                 // 256 blocks = 1 per CU
#define H2O ((size_t)NB * D1)
#define H3O ((size_t)2 * NB * D1)
#define XS_LD 68   // padded x-staging stride, 16B-aligned rows

__device__ __forceinline__ float ftanh(float x)
{
    // tanh(x) = 1 - 2/(exp(2x)+1); safe at +/-inf (rcp(inf)=0 -> 1; e->0 -> -1)
    float e = __expf(2.0f * x);                  // v_mul + v_exp_f32
    float r = __builtin_amdgcn_rcpf(e + 1.0f);   // v_rcp_f32, ~1 ulp
    return fmaf(-2.0f, r, 1.0f);
}

union F4 { float4 v; float f[4]; };

__global__ __launch_bounds__(NT, 1)
void k_fused(const float* __restrict__ x,
             const float* __restrict__ n1, const float* __restrict__ n2,
             const float* __restrict__ n3,
             const float* __restrict__ W0, const float* __restrict__ b0,
             const float* __restrict__ W1, const float* __restrict__ b1,
             const float* __restrict__ W2, const float* __restrict__ b2,
             float* __restrict__ out)
{
    __shared__ float W1L[D1 * D1];       // 64 KB, full-period chunk swizzle
    __shared__ float h1L[ROWS * D1];     // 32 KB
    __shared__ float h2L[ROWS * D1];     // 32 KB
    __shared__ float c1L[ROWS * D1];     // 32 KB  -> total exactly 163840 B
    float* xs = W1L;                     // x staging aliases W1L (phase 1 only)

    const int tid = threadIdx.x;
    const int jg = tid & 31;             // col group (j0 = 4*jg)
    const int j0 = jg * 4;
    const int jg3 = (jg < D3) ? jg : 0;  // clamped W2 row / h3 col (jg>=10 unused)
    const size_t row0 = (size_t)blockIdx.x * ROWS;

    // ---------------- phase 1: c1 = x @ W0^T + b0 -> c1L (all 512 threads)
    {
        const int rgp = tid >> 5;        // 0..15, 4 rows each
        const int rp0 = rgp * 4;
        float c1r[4][4];
        #pragma unroll
        for (int i = 0; i < 4; ++i)
            #pragma unroll
            for (int l = 0; l < 4; ++l) c1r[i][l] = 0.f;

        for (int ch = 0; ch < 13; ++ch) {        // 784 = 12*64 + 16
            const int kb = ch * 64;
            const int klen = (ch < 12) ? 64 : 16;
            const int nv4 = klen >> 2;
            for (int q = tid; q < ROWS * nv4; q += NT) {
                int r = q / nv4, c4 = q - r * nv4;
                *(float4*)&xs[r * XS_LD + 4 * c4] =
                    *(const float4*)(x + (row0 + r) * D0 + kb + 4 * c4);
            }
            __syncthreads();
            for (int k = 0; k < klen; k += 4) {
                F4 xr[4];
                #pragma unroll
                for (int i = 0; i < 4; ++i)
                    xr[i].v = *(const float4*)&xs[(rp0 + i) * XS_LD + k];
                #pragma unroll
                for (int l = 0; l < 4; ++l) {
                    F4 w; w.v = *(const float4*)(W0 + (size_t)(j0 + l) * D0 + kb + k);
                    #pragma unroll
                    for (int kk = 0; kk < 4; ++kk)
                        #pragma unroll
                        for (int i = 0; i < 4; ++i)
                            c1r[i][l] = fmaf(xr[i].f[kk], w.f[kk], c1r[i][l]);
                }
            }
            __syncthreads();             // last xs read done before W1L stage
        }
        #pragma unroll
        for (int i = 0; i < 4; ++i) {
            F4 cv;
            #pragma unroll
            for (int l = 0; l < 4; ++l) cv.f[l] = c1r[i][l] + b0[j0 + l];
            *(float4*)&c1L[(rp0 + i) * D1 + j0] = cv.v;
        }
    }

    // ---------------- stage W1 (swizzled) + init state + n3 -> out exchange
    for (int q = tid; q < 4096; q += NT) {       // 8 float4 per thread
        int r = q >> 5, c4 = q & 31;
        int d = (r << 5) | (c4 ^ (r >> 2));
        ((float4*)W1L)[d] = ((const float4*)W1)[q];  // row-perm write: no conflict
    }
    for (int q = tid; q < ROWS * 32; q += NT) {
        int r = q >> 5, c4 = q & 31;
        *(float4*)&h1L[r * D1 + 4 * c4] = *(const float4*)(n1 + (row0 + r) * D1 + 4 * c4);
        *(float4*)&h2L[r * D1 + 4 * c4] = *(const float4*)(n2 + (row0 + r) * D1 + 4 * c4);
    }
    for (int q = tid; q < ROWS * D3; q += NT)    // h3 state lives in out[H3O..]
        out[H3O + (row0 + q / D3) * D3 + (q % D3)] = n3[(row0 + q / D3) * D3 + (q % D3)];
    __syncthreads();

    // ---------------- T Jacobi steps: wave-specialized, 2 barriers/step
    const int rga = (tid >> 5) & 7;      // 8 row-groups per task
    const int r0 = rga * R;
    const bool taskA = (tid < 256);
    float b1r[4];
    #pragma unroll
    for (int l = 0; l < 4; ++l) b1r[l] = b1[j0 + l];
    const float b2r = (jg < D3) ? b2[jg] : 0.f;

    for (int t = 0; t < TSTEPS; ++t) {
        float acc[R][4];                 // a1 (task A) or a2 (task B)
        float a3[R];
        if (taskA) {
            // ---- task A: a1 = c1 + h2@W1 ; a3 = b2 + h2@W2^T
            #pragma unroll
            for (int i = 0; i < R; ++i) {
                F4 cv; cv.v = *(const float4*)&c1L[(r0 + i) * D1 + j0];
                #pragma unroll
                for (int l = 0; l < 4; ++l) acc[i][l] = cv.f[l];
                a3[i] = b2r;
            }
            // depth-1 weight pipeline: X holds chunk c0's weights, Y c1's.
            F4 waX[4], waY[4];
            #pragma unroll
            for (int kk = 0; kk < 4; ++kk)       // preload chunk 0 (co = jg<<2)
                waX[kk].v = *(const float4*)&W1L[kk * D1 + (jg << 2)];
            for (int cp = 0; cp < 16; ++cp) {
                const int c0 = 2 * cp, c1 = c0 + 1;
                const int k0 = c0 << 2, k1 = k0 + 4;
                {   // prefetch weights for c1
                    const int co = (jg ^ c1) << 2;
                    #pragma unroll
                    for (int kk = 0; kk < 4; ++kk)
                        waY[kk].v = *(const float4*)&W1L[(k1 + kk) * D1 + co];
                }
                {   // chunk c0: w2r FIRST (L1 latency hides under state lgkm)
                    F4 w2r, p2[R];
                    w2r.v = *(const float4*)(W2 + (size_t)jg3 * D1 + k0);
                    #pragma unroll
                    for (int i = 0; i < R; ++i)
                        p2[i].v = *(const float4*)&h2L[(r0 + i) * D1 + k0];
                    #pragma unroll
                    for (int kk = 0; kk < 4; ++kk)
                        #pragma unroll
                        for (int i = 0; i < R; ++i) {
                            #pragma unroll
                            for (int l = 0; l < 4; ++l)
                                acc[i][l] = fmaf(p2[i].f[kk], waX[kk].f[l], acc[i][l]);
                            a3[i] = fmaf(p2[i].f[kk], w2r.f[kk], a3[i]);
                        }
                }
                {   // prefetch weights for next pair's first chunk (clamp @31)
                    const int cn = (cp == 15) ? 31 : c0 + 2;
                    const int kn = cn << 2, co = (jg ^ cn) << 2;
                    #pragma unroll
                    for (int kk = 0; kk < 4; ++kk)
                        waX[kk].v = *(const float4*)&W1L[(kn + kk) * D1 + co];
                }
                {   // chunk c1: FMA with waY
                    F4 w2r, p2[R];
                    w2r.v = *(const float4*)(W2 + (size_t)jg3 * D1 + k1);
                    #pragma unroll
                    for (int i = 0; i < R; ++i)
                        p2[i].v = *(const float4*)&h2L[(r0 + i) * D1 + k1];
                    #pragma unroll
                    for (int kk = 0; kk < 4; ++kk)
                        #pragma unroll
                        for (int i = 0; i < R; ++i) {
                            #pragma unroll
                            for (int l = 0; l < 4; ++l)
                                acc[i][l] = fmaf(p2[i].f[kk], waY[kk].f[l], acc[i][l]);
                            a3[i] = fmaf(p2[i].f[kk], w2r.f[kk], a3[i]);
                        }
                }
            }
        } else {
            // ---- task B: a2 = b1 + h3@W2 + h1@W1^T
            // h3 loads FIRST (own column, 8 scalar VMEM, ~4000cy before use of
            // last one; values from previous step's A-write, visible per bar2)
            float h3own[R];
            #pragma unroll
            for (int i = 0; i < R; ++i)
                h3own[i] = out[H3O + (row0 + r0 + i) * D3 + jg3];
            #pragma unroll
            for (int i = 0; i < R; ++i)
                #pragma unroll
                for (int l = 0; l < 4; ++l) acc[i][l] = b1r[l];
            #pragma unroll
            for (int kk = 0; kk < D3; ++kk) {    // h3 terms up front (shfl bcast)
                F4 wc; wc.v = *(const float4*)(W2 + (size_t)kk * D1 + j0);
                #pragma unroll
                for (int i = 0; i < R; ++i) {
                    float h3v = __shfl(h3own[i], kk, 32);  // lane kk loaded col kk
                    #pragma unroll
                    for (int l = 0; l < 4; ++l)
                        acc[i][l] = fmaf(h3v, wc.f[l], acc[i][l]);
                }
            }
            F4 wbX[4], wbY[4];
            #pragma unroll
            for (int l = 0; l < 4; ++l)          // preload chunk 0 (co = jg<<2)
                wbX[l].v = *(const float4*)&W1L[(j0 + l) * D1 + (jg << 2)];
            for (int cp = 0; cp < 16; ++cp) {
                const int c0 = 2 * cp, c1 = c0 + 1;
                const int k0 = c0 << 2, k1 = k0 + 4;
                {   // prefetch weights for c1
                    const int co = (jg ^ c1) << 2;
                    #pragma unroll
                    for (int l = 0; l < 4; ++l)
                        wbY[l].v = *(const float4*)&W1L[(j0 + l) * D1 + co];
                }
                {   // chunk c0
                    F4 p1[R];
                    #pragma unroll
                    for (int i = 0; i < R; ++i)
                        p1[i].v = *(const float4*)&h1L[(r0 + i) * D1 + k0];
                    #pragma unroll
                    for (int kk = 0; kk < 4; ++kk)
                        #pragma unroll
                        for (int i = 0; i < R; ++i)
                            #pragma unroll
                            for (int l = 0; l < 4; ++l)
                                acc[i][l] = fmaf(p1[i].f[kk], wbX[l].f[kk], acc[i][l]);
                }
                {   // prefetch weights for next pair's first chunk (clamp @31)
                    const int cn = (cp == 15) ? 31 : c0 + 2;
                    const int co = (jg ^ cn) << 2;
                    #pragma unroll
                    for (int l = 0; l < 4; ++l)
                        wbX[l].v = *(const float4*)&W1L[(j0 + l) * D1 + co];
                }
                {   // chunk c1
                    F4 p1[R];
                    #pragma unroll
                    for (int i = 0; i < R; ++i)
                        p1[i].v = *(const float4*)&h1L[(r0 + i) * D1 + k1];
                    #pragma unroll
                    for (int kk = 0; kk < 4; ++kk)
                        #pragma unroll
                        for (int i = 0; i < R; ++i)
                            #pragma unroll
                            for (int l = 0; l < 4; ++l)
                                acc[i][l] = fmaf(p1[i].f[kk], wbY[l].f[kk], acc[i][l]);
                }
            }
        }
        __syncthreads();                 // all reads of old state complete
        if (taskA) {
            #pragma unroll
            for (int i = 0; i < R; ++i)
                *(float4*)&h1L[(r0 + i) * D1 + j0] =
                    make_float4(ftanh(acc[i][0]), ftanh(acc[i][1]),
                                ftanh(acc[i][2]), ftanh(acc[i][3]));
            if (jg < D3) {
                #pragma unroll
                for (int i = 0; i < R; ++i)
                    out[H3O + (row0 + r0 + i) * D3 + jg] = ftanh(a3[i]);
            }
        } else {
            #pragma unroll
            for (int i = 0; i < R; ++i)
                *(float4*)&h2L[(r0 + i) * D1 + j0] =
                    make_float4(ftanh(acc[i][0]), ftanh(acc[i][1]),
                                ftanh(acc[i][2]), ftanh(acc[i][3]));
        }
        __syncthreads();                 // new state (incl. out-h3) visible
    }

    // ---------------- epilogue: h1, h2 (h3 already final in out[H3O..])
    for (int q = tid; q < ROWS * 32; q += NT) {
        int r = q >> 5, c4 = q & 31;
        *(float4*)(out + (row0 + r) * D1 + 4 * c4)       = *(const float4*)&h1L[r * D1 + 4 * c4];
        *(float4*)(out + H2O + (row0 + r) * D1 + 4 * c4) = *(const float4*)&h2L[r * D1 + 4 * c4];
    }
}

extern "C" void kernel_launch(void* const* d_in, const int* in_sizes, int n_in,
                              void* d_out, int out_size, void* d_ws, size_t ws_size,
                              hipStream_t stream) {
    // inputs: 0:x 1:y 2:n1 3:n2 4:n3 5:W0 6:b0 7:W1 8:b1 9:W2 10:b2 11:T(=60 hard-coded)
    const float* x  = (const float*)d_in[0];
    const float* n1 = (const float*)d_in[2];
    const float* n2 = (const float*)d_in[3];
    const float* n3 = (const float*)d_in[4];
    const float* W0 = (const float*)d_in[5];
    const float* b0 = (const float*)d_in[6];
    const float* W1 = (const float*)d_in[7];
    const float* b1 = (const float*)d_in[8];
    const float* W2 = (const float*)d_in[9];
    const float* b2 = (const float*)d_in[10];

    k_fused<<<NBLK, NT, 0, stream>>>(x, n1, n2, n3, W0, b0, W1, b1, W2, b2,
                                     (float*)d_out);

    hipError_t e = hipGetLastError();
    if (e != hipSuccess) {   // surface launch error as fp32 1000+e (free on success)
        static float code[4];
        code[0] = code[1] = code[2] = code[3] = 1000.0f + (float)(int)e;
        hipMemcpyAsync(d_out, code, 4 * sizeof(float), hipMemcpyHostToDevice, stream);
    }
}